// Round 11
// baseline (7020.570 us; speedup 1.0000x reference)
//
#include <hip/hip_runtime.h>
#include <math.h>

#define NN 15000      // nodes
#define NE 60000      // edges
#define DIN 74
#define DEIN 12
#define DD 64         // node feat dim
#define EH 128        // edge hidden
#define NG 8192       // EH*DD
#define NGX 8256      // NG + 64 (Bh fold)
#define NSTEPS 6
#define NPART 938     // ceil(NN/16)

typedef unsigned short ushort_t;
typedef __attribute__((ext_vector_type(8))) short short8v;
typedef __attribute__((ext_vector_type(4))) float float4v;

__device__ __forceinline__ float bsf(unsigned short u){
  union { unsigned int i; float f; } v; v.i = ((unsigned int)u) << 16; return v.f;
}
__device__ __forceinline__ float blo(unsigned int u){
  union { unsigned int i; float f; } v; v.i = u << 16; return v.f;
}
__device__ __forceinline__ float bhi(unsigned int u){
  union { unsigned int i; float f; } v; v.i = u & 0xffff0000u; return v.f;
}
__device__ __forceinline__ unsigned short fsb(float f){
  union { float f; unsigned int i; } v; v.f = f;
  unsigned int x = v.i;
  return (unsigned short)((x + 0x7FFFu + ((x >> 16) & 1u)) >> 16);
}

// ---------- dtype sniff
__global__ void k_sniff(const ushort_t* __restrict__ nf16,
                        const int* __restrict__ dsti, int* __restrict__ flags){
  __shared__ int cnt[2];
  int t = threadIdx.x;
  if (t < 2) cnt[t] = 0;
  __syncthreads();
  int bad = 0;
  for (int i = t; i < 1024; i += 256){
    unsigned short u = nf16[2*i];
    int e = (u >> 7) & 0xFF;
    if (e < 96 || e > 159) bad++;
  }
  if (bad) atomicAdd(&cnt[0], bad);
  if (t < 256 && dsti[2*t+1] == 0) atomicAdd(&cnt[1], 1);
  __syncthreads();
  if (t == 0){
    flags[0] = (cnt[0] > 300) ? 1 : 0;
    flags[1] = (cnt[1] > 250) ? 1 : 0;
  }
}

__global__ void k_canon(const void* __restrict__ in, float* __restrict__ out,
                        int n, const int* __restrict__ flags){
  int i = blockIdx.x*256 + threadIdx.x;
  if (i >= n) return;
  if (flags[0]) out[i] = ((const float*)in)[i];
  else          out[i] = bsf(((const ushort_t*)in)[i]);
}
__global__ void k_canoni(const void* __restrict__ in, int* __restrict__ out,
                         int n, const int* __restrict__ flags){
  int i = blockIdx.x*256 + threadIdx.x;
  if (i >= n) return;
  long long v = flags[1] ? ((const long long*)in)[i]
                         : (long long)((const int*)in)[i];
  int vi = (int)v;
  if (vi < 0) vi = 0;
  if (vi >= NN) vi = NN-1;
  out[i] = vi;
}

// ---------- one-time: h0 = relu(nf @ W_proj + b_proj) -> fp32 + bf16 shadow
__global__ void k_proj(const float* __restrict__ nf, const float* __restrict__ Wp,
                       const float* __restrict__ bp, float* __restrict__ hid,
                       ushort_t* __restrict__ hidb){
  __shared__ float nfl[4][DIN];
  int t = threadIdx.x, blk = blockIdx.x;
  for (int idx = t; idx < 4*DIN; idx += 256){
    int vl = idx / DIN, i = idx - vl*DIN;
    nfl[vl][i] = nf[(size_t)(blk*4+vl)*DIN + i];
  }
  __syncthreads();
  int vl = t >> 6, o = t & 63;
  int v = blk*4 + vl;
  float acc = bp[o];
  for (int i = 0; i < DIN; ++i) acc += nfl[vl][i] * Wp[i*DD + o];
  float r = fmaxf(acc, 0.f);
  hid[(size_t)v*DD + o] = r;
  hidb[(size_t)v*DD + o] = fsb(r);
}

// ---------- one-time: t = relu(ef @ W_e1 + b_e1), fp32
__global__ void k_emlp(const float* __restrict__ ef, const float* __restrict__ W1,
                       const float* __restrict__ b1, float* __restrict__ tfp){
  __shared__ float efl[2][DEIN];
  int t = threadIdx.x, blk = blockIdx.x;
  if (t < 2*DEIN){
    int el = t / DEIN, i = t - el*DEIN;
    efl[el][i] = ef[(size_t)(blk*2+el)*DEIN + i];
  }
  __syncthreads();
  int el = t >> 7, c = t & 127;
  float acc = b1[c];
  for (int i = 0; i < DEIN; ++i) acc += efl[el][i] * W1[i*EH + c];
  tfp[(size_t)(blk*2+el)*EH + c] = fmaxf(acc, 0.f);
}

// ---------- one-time: w2rtx rows permuted so G comes out o-major:
// row n' < 8192: o = n'>>7, k = n'&127, w2rtx[n'][i] = W2[k][i*64+o]
// row n' >= 8192: o = n'-8192, w2rtx[n'][i] = b2[i*64+o]   (Bh fold)
__global__ void k_w2rtx(const float* __restrict__ W2, const float* __restrict__ b2,
                        ushort_t* __restrict__ w2rtx){
  int idx = blockIdx.x*256 + threadIdx.x;
  if (idx < NGX*DD){
    int n = idx >> 6, i = idx & 63;
    float v;
    if (n < NG){
      int o = n >> 7, k = n & 127;
      v = W2[(size_t)k*4096 + i*64 + o];
    } else {
      v = b2[i*64 + (n - NG)];
    }
    w2rtx[idx] = fsb(v);
  }
}

// ---------- CSR build
__global__ void k_zero(int* __restrict__ p, int n){
  int i = blockIdx.x*256 + threadIdx.x;
  if (i < n) p[i] = 0;
}
__global__ void k_deg(const int* __restrict__ idxarr, int* __restrict__ deg){
  int e = blockIdx.x*256 + threadIdx.x;
  if (e < NE) atomicAdd(&deg[idxarr[e]], 1);
}
__global__ void k_scan(const int* __restrict__ deg, int* __restrict__ rowp,
                       float* __restrict__ invd){
  __shared__ int ssum[256];
  int t = threadIdx.x;
  const int STRIP = (NN + 255) / 256;
  int lo = t*STRIP, hi = (lo + STRIP < NN) ? lo + STRIP : NN;
  int s = 0;
  for (int i = lo; i < hi; ++i) s += deg[i];
  ssum[t] = s;
  __syncthreads();
  if (t == 0){
    int acc = 0;
    for (int i = 0; i < 256; ++i){ int v = ssum[i]; ssum[i] = acc; acc += v; }
  }
  __syncthreads();
  int acc = ssum[t];
  for (int i = lo; i < hi; ++i){
    rowp[i] = acc;
    int d = deg[i];
    invd[i] = (d > 0) ? 1.0f/(float)d : 0.0f;
    acc += d;
  }
  if (t == 255) rowp[NN] = acc;
}
__global__ void k_scatter(const int* __restrict__ idxarr, const int* __restrict__ rowp,
                          int* __restrict__ cursor, int* __restrict__ eidx){
  int e = blockIdx.x*256 + threadIdx.x;
  if (e < NE){
    int d = idxarr[e];
    int pos = atomicAdd(&cursor[d], 1);
    eidx[rowp[d] + pos] = e;
  }
}

// ---------- per chunk: G[m][n'] = hidb[chunk0+m] @ w2rtx  (bf16 MFMA)
__global__ __launch_bounds__(256) void k_ggemm(const ushort_t* __restrict__ hidb,
        const ushort_t* __restrict__ w2rtx, ushort_t* __restrict__ G,
        int chunk0, int cact){
  __shared__ __align__(16) ushort_t As[64][72];
  __shared__ __align__(16) ushort_t Bs[64][72];
  int t = threadIdx.x;
  int n0 = blockIdx.x * 64;
  int m0 = blockIdx.y * 64;
  #pragma unroll
  for (int it = 0; it < 2; ++it){
    int cid = t + it*256;
    int r = cid >> 3, ko = (cid & 7) * 8;
    int gm = chunk0 + m0 + r; if (gm >= NN) gm = NN-1;   // clamp; store guarded
    *(uint4*)&As[r][ko] = *(const uint4*)(hidb + (size_t)gm*DD + ko);
    *(uint4*)&Bs[r][ko] = *(const uint4*)(w2rtx + (size_t)(n0 + r)*DD + ko);
  }
  __syncthreads();
  int w = t >> 6, lane = t & 63;
  int lrow = lane & 15, quad = lane >> 4;
  float4v acc[4];
  #pragma unroll
  for (int nt = 0; nt < 4; ++nt) acc[nt] = (float4v){0.f,0.f,0.f,0.f};
  #pragma unroll
  for (int ks = 0; ks < 2; ++ks){
    short8v a = *(const short8v*)&As[w*16 + lrow][ks*32 + quad*8];
    #pragma unroll
    for (int nt = 0; nt < 4; ++nt){
      short8v b = *(const short8v*)&Bs[nt*16 + lrow][ks*32 + quad*8];
      acc[nt] = __builtin_amdgcn_mfma_f32_16x16x32_bf16(a, b, acc[nt], 0, 0, 0);
    }
  }
  #pragma unroll
  for (int nt = 0; nt < 4; ++nt){
    int col = n0 + nt*16 + lrow;
    #pragma unroll
    for (int reg = 0; reg < 4; ++reg){
      int m = m0 + w*16 + quad*4 + reg;
      if (m < cact) G[(size_t)m*NGX + col] = fsb(acc[nt][reg]);
    }
  }
}

// ---------- per chunk: msg[e,o] = sum_k t[e,k]*G[src][o*128+k] + G[src][8192+o]
// G row staged in LDS once per node (XOR-swizzled b128), edges reuse from LDS.
__global__ __launch_bounds__(256) void k_edge(const float* __restrict__ tfp,
      const ushort_t* __restrict__ G,
      const int* __restrict__ rowp2, const int* __restrict__ eidx2,
      float* __restrict__ msg, int chunk0){
  __shared__ __align__(16) ushort_t gl[NG];    // 16 KB, swizzled per-o chunks
  __shared__ __align__(16) ushort_t bhl[64];
  __shared__ __align__(16) float tl[4][128];   // 2 KB
  __shared__ int eids[4];
  int t = threadIdx.x;
  int vloc = blockIdx.x;
  int v = chunk0 + vloc;
  int b = rowp2[v], e_end = rowp2[v+1];
  if (b == e_end) return;                      // block-uniform
  const ushort_t* grow = G + (size_t)vloc*NGX;
  for (int idx = t; idx < 1032; idx += 256){   // 1032 uint4 = 8256 bf16, coalesced
    uint4 val = *(const uint4*)(grow + idx*8);
    if (idx < 1024){
      int o = idx >> 4, c = idx & 15;
      *(uint4*)&gl[o*128 + ((c ^ (o & 15)) << 3)] = val;
    } else {
      *(uint4*)&bhl[(idx - 1024)*8] = val;
    }
  }
  int w = t >> 6, o = t & 63;
  int sw = o & 15;
  const uint4* gv = (const uint4*)&gl[o*128];  // 16 swizzled chunks of 8 bf16
  for (int base = b; base < e_end; base += 4){
    __syncthreads();                           // also covers gl/bhl visibility
    if (t < 4){
      int ei = base + t;
      eids[t] = (ei < e_end) ? eidx2[ei] : -1;
    }
    __syncthreads();
    for (int idx = t; idx < 512; idx += 256){
      int slot = idx >> 7, k = idx & 127;
      int e = eids[slot];
      tl[slot][k] = (e >= 0) ? tfp[(size_t)e*EH + k] : 0.f;
    }
    __syncthreads();
    int e = eids[w];
    if (e >= 0){
      float acc = bsf(bhl[o]);
      #pragma unroll
      for (int c = 0; c < 16; ++c){
        uint4 g8 = gv[c ^ sw];
        float4 ta = *(const float4*)&tl[w][c*8];
        float4 tb = *(const float4*)&tl[w][c*8 + 4];
        acc += ta.x*blo(g8.x) + ta.y*bhi(g8.x) + ta.z*blo(g8.y) + ta.w*bhi(g8.y);
        acc += tb.x*blo(g8.z) + tb.y*bhi(g8.z) + tb.z*blo(g8.w) + tb.w*bhi(g8.w);
      }
      msg[(size_t)e*DD + o] = acc;
    }
  }
}

// ---------- per step: rst = mean msg + bias; fused BN column partials
__global__ __launch_bounds__(256) void k_aggrbn(const float* __restrict__ msg,
      const int* __restrict__ rowp, const int* __restrict__ eidx,
      const float* __restrict__ invd, const float* __restrict__ cbias,
      float* __restrict__ rst, float* __restrict__ part){
  __shared__ float ls[4][64], ls2[4][64];
  int t = threadIdx.x, blk = blockIdx.x;
  int o = t & 63, w = t >> 6;
  float cb = cbias[o];
  float s = 0.f, s2 = 0.f;
  #pragma unroll
  for (int j = 0; j < 4; ++j){
    int v = blk*16 + w*4 + j;
    if (v < NN){
      float acc = 0.f;
      int b = rowp[v], e2 = rowp[v+1];
      for (int idx = b; idx < e2; ++idx)
        acc += msg[(size_t)eidx[idx]*DD + o];
      float r = acc*invd[v] + cb;
      rst[(size_t)v*DD + o] = r;
      s += r; s2 += r*r;
    }
  }
  ls[w][o] = s; ls2[w][o] = s2;
  __syncthreads();
  if (w == 0){
    part[blk*128 + o]      = ls[0][o]+ls[1][o]+ls[2][o]+ls[3][o];
    part[blk*128 + 64 + o] = ls2[0][o]+ls2[1][o]+ls2[2][o]+ls2[3][o];
  }
}
__global__ void k_bnf(const float* __restrict__ part, float* __restrict__ stats){
  __shared__ float sh[128];
  int t = threadIdx.x;  // 128 threads
  float s = 0.f;
  for (int b = 0; b < NPART; ++b) s += part[b*128 + t];
  sh[t] = s;
  __syncthreads();
  if (t < 64){
    float mu = sh[t] / (float)NN;
    float var = sh[64+t] / (float)NN - mu*mu;
    if (var < 0.f) var = 0.f;
    stats[t] = mu;
    stats[64 + t] = rsqrtf(var + 1e-5f);
  }
}

// ---------- per step: GRU, 16 nodes/block, b128 LDS everywhere
__global__ __launch_bounds__(256) void k_gru(const float* __restrict__ rst,
      const float* __restrict__ stats,
      const float* __restrict__ gamma, const float* __restrict__ beta,
      const float* __restrict__ Wih, const float* __restrict__ Whh,
      const float* __restrict__ bih, const float* __restrict__ bhh,
      float* __restrict__ hid, ushort_t* __restrict__ hidb,
      float* __restrict__ out, int write_out){
  __shared__ __align__(16) float ml[16][68], hl[16][68];
  __shared__ __align__(16) float wtI[64*64], wtH[64*64];  // per-gate, swizzled
  int t = threadIdx.x, blk = blockIdx.x;
  int o = t & 63, w = t >> 6;
  int sw = o & 15;
  float st_mu = stats[o], st_rs = stats[64+o], ga = gamma[o], be = beta[o];
  #pragma unroll
  for (int j = 0; j < 4; ++j){
    int n = w*4 + j;
    int v = blk*16 + n;
    float x  = (v < NN) ? rst[(size_t)v*DD + o] : 0.f;
    float hp = (v < NN) ? hid[(size_t)v*DD + o] : 0.f;
    ml[n][o] = fmaxf((x - st_mu)*st_rs*ga + be, 0.f);
    hl[n][o] = hp;
  }
  float accI[3][4], accH[3][4];
  #pragma unroll
  for (int g = 0; g < 3; ++g){
    float bi = bih[g*64+o], bh = bhh[g*64+o];
    #pragma unroll
    for (int j = 0; j < 4; ++j){ accI[g][j] = bi; accH[g][j] = bh; }
  }
  #pragma unroll
  for (int g = 0; g < 3; ++g){
    __syncthreads();
    for (int idx = t; idx < 1024; idx += 256){   // 64 rows x 16 chunks, coalesced
      int row = idx >> 4, c = idx & 15;
      int dst = row*64 + ((c ^ (row & 15)) << 2);
      *(float4*)&wtI[dst] = *(const float4*)(Wih + (size_t)(g*64+row)*64 + c*4);
      *(float4*)&wtH[dst] = *(const float4*)(Whh + (size_t)(g*64+row)*64 + c*4);
    }
    __syncthreads();
    #pragma unroll
    for (int c = 0; c < 16; ++c){
      float4 wi = *(const float4*)&wtI[o*64 + ((c ^ sw) << 2)];
      float4 wh = *(const float4*)&wtH[o*64 + ((c ^ sw) << 2)];
      #pragma unroll
      for (int j = 0; j < 4; ++j){
        int n = w*4 + j;
        float4 m4 = *(const float4*)&ml[n][c*4];
        float4 h4 = *(const float4*)&hl[n][c*4];
        accI[g][j] += m4.x*wi.x + m4.y*wi.y + m4.z*wi.z + m4.w*wi.w;
        accH[g][j] += h4.x*wh.x + h4.y*wh.y + h4.z*wh.z + h4.w*wh.w;
      }
    }
  }
  #pragma unroll
  for (int j = 0; j < 4; ++j){
    int n = w*4 + j;
    int v = blk*16 + n;
    if (v < NN){
      float r  = 1.f/(1.f+__expf(-(accI[0][j]+accH[0][j])));
      float z  = 1.f/(1.f+__expf(-(accI[1][j]+accH[1][j])));
      float nn_= tanhf(accI[2][j] + r*accH[2][j]);
      float hnew = (1.f - z)*nn_ + z*hl[n][o];
      hid[(size_t)v*DD + o] = hnew;
      hidb[(size_t)v*DD + o] = fsb(hnew);
      if (write_out) out[(size_t)v*DD + o] = hnew;
    }
  }
}

extern "C" void kernel_launch(void* const* d_in, const int* in_sizes, int n_in,
                              void* d_out, int out_size, void* d_ws, size_t ws_size,
                              hipStream_t stream){
  (void)out_size;
  float* out = (float*)d_out;

  // resolve input positions by size (== dict order on this instance)
  int p_nf=-1,p_ef=-1,p_src=-1,p_dst=-1,p_Wp=-1,p_bp=-1,p_W1=-1,p_b1=-1,
      p_W2=-1,p_b2=-1,p_cb=-1,p_gam=-1,p_bet=-1,p_Wih=-1,p_Whh=-1,p_bih=-1,p_bhh=-1;
  int c60000=0,c64=0,c12288=0,c192=0;
  for (int i = 0; i < n_in; ++i){
    switch (in_sizes[i]){
      case 1110000: p_nf = i; break;
      case 720000:  p_ef = i; break;
      case 60000:   if (c60000++ == 0) p_src = i; else p_dst = i; break;
      case 4736:    p_Wp = i; break;
      case 64:      { if (c64==0) p_bp=i; else if (c64==1) p_cb=i;
                      else if (c64==2) p_gam=i; else p_bet=i; c64++; } break;
      case 1536:    p_W1 = i; break;
      case 128:     p_b1 = i; break;
      case 524288:  p_W2 = i; break;
      case 4096:    p_b2 = i; break;
      case 12288:   if (c12288++ == 0) p_Wih = i; else p_Whh = i; break;
      case 192:     if (c192++ == 0) p_bih = i; else p_bhh = i; break;
      default: break;
    }
  }

  char* p = (char*)d_ws;
  auto alloc = [&](size_t bytes)->char*{
    char* r = p; p += (bytes + 255) & ~(size_t)255; return r;
  };
  int* flags = (int*)alloc(256);
  const int FPOS[15] = {p_nf,p_ef,p_Wp,p_bp,p_W1,p_b1,p_W2,p_b2,p_cb,p_gam,p_bet,
                        p_Wih,p_Whh,p_bih,p_bhh};
  float* canon[15];
  for (int j = 0; j < 15; ++j)
    canon[j] = (float*)alloc((size_t)in_sizes[FPOS[j]] * 4);
  const float* nf  = canon[0];  const float* ef  = canon[1];
  const float* Wp  = canon[2];  const float* bp  = canon[3];
  const float* W1  = canon[4];  const float* b1  = canon[5];
  const float* W2  = canon[6];  const float* b2  = canon[7];
  const float* cb  = canon[8];  const float* gam = canon[9];
  const float* bet = canon[10]; const float* Wih = canon[11];
  const float* Whh = canon[12]; const float* bih = canon[13];
  const float* bhh = canon[14];
  int* srcc = (int*)alloc((size_t)NE*4);
  int* dstc = (int*)alloc((size_t)NE*4);

  float* tfp      = (float*)alloc((size_t)NE*EH*4);     // 30.7 MB
  ushort_t* w2rtx = (ushort_t*)alloc((size_t)NGX*DD*2); // 1.06 MB
  float* hid      = (float*)alloc((size_t)NN*DD*4);
  ushort_t* hidb  = (ushort_t*)alloc((size_t)NN*DD*2);
  float* msg      = (float*)alloc((size_t)NE*DD*4);     // 15.4 MB
  float* rst      = (float*)alloc((size_t)NN*DD*4);
  float* part     = (float*)alloc((size_t)NPART*128*4);
  float* stats    = (float*)alloc(128*4);
  int* degall     = (int*)alloc((size_t)4*NN*4);
  int* deg  = degall;        int* cursor  = degall + NN;
  int* deg2 = degall + 2*NN; int* cursor2 = degall + 3*NN;
  int* rowp   = (int*)alloc((size_t)(NN+1)*4);
  float* invd = (float*)alloc((size_t)NN*4);
  int* eidx   = (int*)alloc((size_t)NE*4);
  int* rowp2  = (int*)alloc((size_t)(NN+1)*4);
  float* invd2= (float*)alloc((size_t)NN*4);
  int* eidx2  = (int*)alloc((size_t)NE*4);

  // adaptive bf16 G-chunk (deterministic per ws_size)
  size_t used = (size_t)(p - (char*)d_ws);
  size_t rem = (ws_size > used) ? (ws_size - used) : 0;
  long long Cll = (long long)(rem / ((size_t)NGX*2));
  int C = (Cll > 15040) ? 15040 : (int)Cll;
  C &= ~63;
  if (C > 4096) C = 4096;   // ~68 MB bf16 G-chunk, L3-resident
  if (C < 64)  C = 64;
  ushort_t* G = (ushort_t*)alloc((size_t)C*NGX*2);
  int nch = (NN + C - 1) / C;

  k_sniff<<<1, 256, 0, stream>>>((const ushort_t*)d_in[p_nf], (const int*)d_in[p_dst], flags);
  for (int j = 0; j < 15; ++j){
    int n = in_sizes[FPOS[j]];
    k_canon<<<(n+255)/256, 256, 0, stream>>>(d_in[FPOS[j]], canon[j], n, flags);
  }
  k_canoni<<<(NE+255)/256, 256, 0, stream>>>(d_in[p_src], srcc, NE, flags);
  k_canoni<<<(NE+255)/256, 256, 0, stream>>>(d_in[p_dst], dstc, NE, flags);

  k_proj <<<NN/4,  256, 0, stream>>>(nf, Wp, bp, hid, hidb);
  k_emlp <<<NE/2,  256, 0, stream>>>(ef, W1, b1, tfp);
  k_w2rtx<<<(NGX*DD+255)/256, 256, 0, stream>>>(W2, b2, w2rtx);
  k_zero <<<(4*NN+255)/256, 256, 0, stream>>>(degall, 4*NN);
  k_deg  <<<(NE+255)/256, 256, 0, stream>>>(dstc, deg);
  k_deg  <<<(NE+255)/256, 256, 0, stream>>>(srcc, deg2);
  k_scan <<<1, 256, 0, stream>>>(deg, rowp, invd);
  k_scan <<<1, 256, 0, stream>>>(deg2, rowp2, invd2);
  k_scatter<<<(NE+255)/256, 256, 0, stream>>>(dstc, rowp, cursor, eidx);
  k_scatter<<<(NE+255)/256, 256, 0, stream>>>(srcc, rowp2, cursor2, eidx2);

  for (int s = 0; s < NSTEPS; ++s){
    for (int c = 0; c < nch; ++c){
      int chunk0 = c*C;
      int cact = (NN - chunk0 < C) ? (NN - chunk0) : C;
      k_ggemm<<<dim3(NGX/64, (cact+63)/64), 256, 0, stream>>>(hidb, w2rtx, G, chunk0, cact);
      k_edge <<<cact, 256, 0, stream>>>(tfp, G, rowp2, eidx2, msg, chunk0);
    }
    k_aggrbn<<<NPART, 256, 0, stream>>>(msg, rowp, eidx, invd, cb, rst, part);
    k_bnf   <<<1, 128, 0, stream>>>(part, stats);
    k_gru   <<<NPART, 256, 0, stream>>>(rst, stats, gam, bet, Wih, Whh, bih, bhh,
                                        hid, hidb, out, (s == NSTEPS-1) ? 1 : 0);
  }
}

// Round 12
// 1538.563 us; speedup vs baseline: 4.5631x; 4.5631x over previous
//
#include <hip/hip_runtime.h>
#include <math.h>

#define NN 15000      // nodes
#define NE 60000      // edges
#define DIN 74
#define DEIN 12
#define DD 64         // node feat dim
#define EH 128        // edge hidden
#define NG 8192       // EH*DD
#define NGX 8256      // NG + 64 (Bh fold)
#define NSTEPS 6
#define NPART 938     // ceil(NN/16)

typedef unsigned short ushort_t;
typedef __attribute__((ext_vector_type(8))) short short8v;
typedef __attribute__((ext_vector_type(4))) float float4v;

__device__ __forceinline__ float bsf(unsigned short u){
  union { unsigned int i; float f; } v; v.i = ((unsigned int)u) << 16; return v.f;
}
__device__ __forceinline__ float blo(unsigned int u){
  union { unsigned int i; float f; } v; v.i = u << 16; return v.f;
}
__device__ __forceinline__ float bhi(unsigned int u){
  union { unsigned int i; float f; } v; v.i = u & 0xffff0000u; return v.f;
}
__device__ __forceinline__ unsigned short fsb(float f){
  union { float f; unsigned int i; } v; v.f = f;
  unsigned int x = v.i;
  return (unsigned short)((x + 0x7FFFu + ((x >> 16) & 1u)) >> 16);
}

// ---------- dtype sniff
__global__ void k_sniff(const ushort_t* __restrict__ nf16,
                        const int* __restrict__ dsti, int* __restrict__ flags){
  __shared__ int cnt[2];
  int t = threadIdx.x;
  if (t < 2) cnt[t] = 0;
  __syncthreads();
  int bad = 0;
  for (int i = t; i < 1024; i += 256){
    unsigned short u = nf16[2*i];
    int e = (u >> 7) & 0xFF;
    if (e < 96 || e > 159) bad++;
  }
  if (bad) atomicAdd(&cnt[0], bad);
  if (t < 256 && dsti[2*t+1] == 0) atomicAdd(&cnt[1], 1);
  __syncthreads();
  if (t == 0){
    flags[0] = (cnt[0] > 300) ? 1 : 0;
    flags[1] = (cnt[1] > 250) ? 1 : 0;
  }
}

// ---------- batched canonicalization: 15 tensors in one dispatch
struct CanonArgs {
  const void* in[15];
  float* out[15];
  int n[15];
};
__global__ void k_canon_all(CanonArgs a, const int* __restrict__ flags){
  int j = blockIdx.y;
  int n = a.n[j];
  int fp32 = flags[0];
  const void* in = a.in[j];
  float* out = a.out[j];
  for (int i = blockIdx.x*256 + threadIdx.x; i < n; i += gridDim.x*256){
    if (fp32) out[i] = ((const float*)in)[i];
    else      out[i] = bsf(((const ushort_t*)in)[i]);
  }
}
__global__ void k_canoni(const void* __restrict__ in, int* __restrict__ out,
                         int n, const int* __restrict__ flags){
  int i = blockIdx.x*256 + threadIdx.x;
  if (i >= n) return;
  long long v = flags[1] ? ((const long long*)in)[i]
                         : (long long)((const int*)in)[i];
  int vi = (int)v;
  if (vi < 0) vi = 0;
  if (vi >= NN) vi = NN-1;
  out[i] = vi;
}

// ---------- one-time: h0 = relu(nf @ W_proj + b_proj) -> fp32 + bf16 shadow
__global__ void k_proj(const float* __restrict__ nf, const float* __restrict__ Wp,
                       const float* __restrict__ bp, float* __restrict__ hid,
                       ushort_t* __restrict__ hidb){
  __shared__ float nfl[4][DIN];
  int t = threadIdx.x, blk = blockIdx.x;
  for (int idx = t; idx < 4*DIN; idx += 256){
    int vl = idx / DIN, i = idx - vl*DIN;
    nfl[vl][i] = nf[(size_t)(blk*4+vl)*DIN + i];
  }
  __syncthreads();
  int vl = t >> 6, o = t & 63;
  int v = blk*4 + vl;
  float acc = bp[o];
  for (int i = 0; i < DIN; ++i) acc += nfl[vl][i] * Wp[i*DD + o];
  float r = fmaxf(acc, 0.f);
  hid[(size_t)v*DD + o] = r;
  hidb[(size_t)v*DD + o] = fsb(r);
}

// ---------- one-time: t = relu(ef @ W_e1 + b_e1), fp32
__global__ void k_emlp(const float* __restrict__ ef, const float* __restrict__ W1,
                       const float* __restrict__ b1, float* __restrict__ tfp){
  __shared__ float efl[2][DEIN];
  int t = threadIdx.x, blk = blockIdx.x;
  if (t < 2*DEIN){
    int el = t / DEIN, i = t - el*DEIN;
    efl[el][i] = ef[(size_t)(blk*2+el)*DEIN + i];
  }
  __syncthreads();
  int el = t >> 7, c = t & 127;
  float acc = b1[c];
  for (int i = 0; i < DEIN; ++i) acc += efl[el][i] * W1[i*EH + c];
  tfp[(size_t)(blk*2+el)*EH + c] = fmaxf(acc, 0.f);
}

// ---------- one-time: w2rtx rows permuted so G comes out o-major
__global__ void k_w2rtx(const float* __restrict__ W2, const float* __restrict__ b2,
                        ushort_t* __restrict__ w2rtx){
  int idx = blockIdx.x*256 + threadIdx.x;
  if (idx < NGX*DD){
    int n = idx >> 6, i = idx & 63;
    float v;
    if (n < NG){
      int o = n >> 7, k = n & 127;
      v = W2[(size_t)k*4096 + i*64 + o];
    } else {
      v = b2[i*64 + (n - NG)];
    }
    w2rtx[idx] = fsb(v);
  }
}

// ---------- CSR build
__global__ void k_zero(int* __restrict__ p, int n){
  int i = blockIdx.x*256 + threadIdx.x;
  if (i < n) p[i] = 0;
}
__global__ void k_deg(const int* __restrict__ idxarr, int* __restrict__ deg){
  int e = blockIdx.x*256 + threadIdx.x;
  if (e < NE) atomicAdd(&deg[idxarr[e]], 1);
}
__global__ void k_scan(const int* __restrict__ deg, int* __restrict__ rowp,
                       float* __restrict__ invd){
  __shared__ int ssum[256];
  int t = threadIdx.x;
  const int STRIP = (NN + 255) / 256;
  int lo = t*STRIP, hi = (lo + STRIP < NN) ? lo + STRIP : NN;
  int s = 0;
  for (int i = lo; i < hi; ++i) s += deg[i];
  ssum[t] = s;
  __syncthreads();
  if (t == 0){
    int acc = 0;
    for (int i = 0; i < 256; ++i){ int v = ssum[i]; ssum[i] = acc; acc += v; }
  }
  __syncthreads();
  int acc = ssum[t];
  for (int i = lo; i < hi; ++i){
    rowp[i] = acc;
    int d = deg[i];
    invd[i] = (d > 0) ? 1.0f/(float)d : 0.0f;
    acc += d;
  }
  if (t == 255) rowp[NN] = acc;
}
__global__ void k_scatter(const int* __restrict__ idxarr, const int* __restrict__ rowp,
                          int* __restrict__ cursor, int* __restrict__ eidx){
  int e = blockIdx.x*256 + threadIdx.x;
  if (e < NE){
    int d = idxarr[e];
    int pos = atomicAdd(&cursor[d], 1);
    eidx[rowp[d] + pos] = e;
  }
}

// ---------- per chunk: G[m][n'] = hidb[chunk0+m] @ w2rtx  (bf16 MFMA)
__global__ __launch_bounds__(256) void k_ggemm(const ushort_t* __restrict__ hidb,
        const ushort_t* __restrict__ w2rtx, ushort_t* __restrict__ G,
        int chunk0, int cact){
  __shared__ __align__(16) ushort_t As[64][72];
  __shared__ __align__(16) ushort_t Bs[64][72];
  int t = threadIdx.x;
  int n0 = blockIdx.x * 64;
  int m0 = blockIdx.y * 64;
  #pragma unroll
  for (int it = 0; it < 2; ++it){
    int cid = t + it*256;
    int r = cid >> 3, ko = (cid & 7) * 8;
    int gm = chunk0 + m0 + r; if (gm >= NN) gm = NN-1;   // clamp; store guarded
    *(uint4*)&As[r][ko] = *(const uint4*)(hidb + (size_t)gm*DD + ko);
    *(uint4*)&Bs[r][ko] = *(const uint4*)(w2rtx + (size_t)(n0 + r)*DD + ko);
  }
  __syncthreads();
  int w = t >> 6, lane = t & 63;
  int lrow = lane & 15, quad = lane >> 4;
  float4v acc[4];
  #pragma unroll
  for (int nt = 0; nt < 4; ++nt) acc[nt] = (float4v){0.f,0.f,0.f,0.f};
  #pragma unroll
  for (int ks = 0; ks < 2; ++ks){
    short8v a = *(const short8v*)&As[w*16 + lrow][ks*32 + quad*8];
    #pragma unroll
    for (int nt = 0; nt < 4; ++nt){
      short8v b = *(const short8v*)&Bs[nt*16 + lrow][ks*32 + quad*8];
      acc[nt] = __builtin_amdgcn_mfma_f32_16x16x32_bf16(a, b, acc[nt], 0, 0, 0);
    }
  }
  #pragma unroll
  for (int nt = 0; nt < 4; ++nt){
    int col = n0 + nt*16 + lrow;
    #pragma unroll
    for (int reg = 0; reg < 4; ++reg){
      int m = m0 + w*16 + quad*4 + reg;
      if (m < cact) G[(size_t)m*NGX + col] = fsb(acc[nt][reg]);
    }
  }
}

// ---------- per chunk: msg[e,o] = sum_k t[e,k]*G[src][o*128+k] + G[src][8192+o]
__global__ __launch_bounds__(256) void k_edge(const float* __restrict__ tfp,
      const ushort_t* __restrict__ G,
      const int* __restrict__ rowp2, const int* __restrict__ eidx2,
      float* __restrict__ msg, int chunk0){
  __shared__ __align__(16) ushort_t gl[NG];    // 16 KB, swizzled per-o chunks
  __shared__ __align__(16) ushort_t bhl[64];
  __shared__ __align__(16) float tl[4][128];   // 2 KB
  __shared__ int eids[4];
  int t = threadIdx.x;
  int vloc = blockIdx.x;
  int v = chunk0 + vloc;
  int b = rowp2[v], e_end = rowp2[v+1];
  if (b == e_end) return;                      // block-uniform
  const ushort_t* grow = G + (size_t)vloc*NGX;
  for (int idx = t; idx < 1032; idx += 256){   // 1032 uint4 = 8256 bf16, coalesced
    uint4 val = *(const uint4*)(grow + idx*8);
    if (idx < 1024){
      int o = idx >> 4, c = idx & 15;
      *(uint4*)&gl[o*128 + ((c ^ (o & 15)) << 3)] = val;
    } else {
      *(uint4*)&bhl[(idx - 1024)*8] = val;
    }
  }
  int w = t >> 6, o = t & 63;
  int sw = o & 15;
  const uint4* gv = (const uint4*)&gl[o*128];  // 16 swizzled chunks of 8 bf16
  for (int base = b; base < e_end; base += 4){
    __syncthreads();                           // also covers gl/bhl visibility
    if (t < 4){
      int ei = base + t;
      eids[t] = (ei < e_end) ? eidx2[ei] : -1;
    }
    __syncthreads();
    for (int idx = t; idx < 512; idx += 256){
      int slot = idx >> 7, k = idx & 127;
      int e = eids[slot];
      tl[slot][k] = (e >= 0) ? tfp[(size_t)e*EH + k] : 0.f;
    }
    __syncthreads();
    int e = eids[w];
    if (e >= 0){
      float acc = bsf(bhl[o]);
      #pragma unroll
      for (int c = 0; c < 16; ++c){
        uint4 g8 = gv[c ^ sw];
        float4 ta = *(const float4*)&tl[w][c*8];
        float4 tb = *(const float4*)&tl[w][c*8 + 4];
        acc += ta.x*blo(g8.x) + ta.y*bhi(g8.x) + ta.z*blo(g8.y) + ta.w*bhi(g8.y);
        acc += tb.x*blo(g8.z) + tb.y*bhi(g8.z) + tb.z*blo(g8.w) + tb.w*bhi(g8.w);
      }
      msg[(size_t)e*DD + o] = acc;
    }
  }
}

// ---------- per step: rst = mean msg + bias; fused BN column partials
__global__ __launch_bounds__(256) void k_aggrbn(const float* __restrict__ msg,
      const int* __restrict__ rowp, const int* __restrict__ eidx,
      const float* __restrict__ invd, const float* __restrict__ cbias,
      float* __restrict__ rst, float* __restrict__ part){
  __shared__ float ls[4][64], ls2[4][64];
  int t = threadIdx.x, blk = blockIdx.x;
  int o = t & 63, w = t >> 6;
  float cb = cbias[o];
  float s = 0.f, s2 = 0.f;
  #pragma unroll
  for (int j = 0; j < 4; ++j){
    int v = blk*16 + w*4 + j;
    if (v < NN){
      float acc = 0.f;
      int b = rowp[v], e2 = rowp[v+1];
      for (int idx = b; idx < e2; ++idx)
        acc += msg[(size_t)eidx[idx]*DD + o];
      float r = acc*invd[v] + cb;
      rst[(size_t)v*DD + o] = r;
      s += r; s2 += r*r;
    }
  }
  ls[w][o] = s; ls2[w][o] = s2;
  __syncthreads();
  if (w == 0){
    part[blk*128 + o]      = ls[0][o]+ls[1][o]+ls[2][o]+ls[3][o];
    part[blk*128 + 64 + o] = ls2[0][o]+ls2[1][o]+ls2[2][o]+ls2[3][o];
  }
}
__global__ void k_bnf(const float* __restrict__ part, float* __restrict__ stats){
  __shared__ float sh[128];
  int t = threadIdx.x;  // 128 threads
  float s = 0.f;
  for (int b = 0; b < NPART; ++b) s += part[b*128 + t];
  sh[t] = s;
  __syncthreads();
  if (t < 64){
    float mu = sh[t] / (float)NN;
    float var = sh[64+t] / (float)NN - mu*mu;
    if (var < 0.f) var = 0.f;
    stats[t] = mu;
    stats[64 + t] = rsqrtf(var + 1e-5f);
  }
}

// ---------- per step: GRU, 16 nodes/block, LDS-transposed weight tiles
// (round-10 version verbatim — measured 50 µs, VGPR 68, no spill)
__global__ __launch_bounds__(256) void k_gru(const float* __restrict__ rst,
      const float* __restrict__ stats,
      const float* __restrict__ gamma, const float* __restrict__ beta,
      const float* __restrict__ Wih, const float* __restrict__ Whh,
      const float* __restrict__ bih, const float* __restrict__ bhh,
      float* __restrict__ hid, ushort_t* __restrict__ hidb,
      float* __restrict__ out, int write_out){
  __shared__ float ml[16][65], hl[16][65];
  __shared__ float wtI[64][65], wtH[64][65];
  int t = threadIdx.x, blk = blockIdx.x;
  int o = t & 63, w = t >> 6;
  float st_mu = stats[o], st_rs = stats[64+o], ga = gamma[o], be = beta[o];
  #pragma unroll
  for (int j = 0; j < 4; ++j){
    int n = w*4 + j;
    int v = blk*16 + n;
    float x  = (v < NN) ? rst[(size_t)v*DD + o] : 0.f;
    float hp = (v < NN) ? hid[(size_t)v*DD + o] : 0.f;
    ml[n][o] = fmaxf((x - st_mu)*st_rs*ga + be, 0.f);
    hl[n][o] = hp;
  }
  float accI[3][4], accH[3][4];
  #pragma unroll
  for (int g = 0; g < 3; ++g){
    float bi = bih[g*64+o], bh = bhh[g*64+o];
    #pragma unroll
    for (int j = 0; j < 4; ++j){ accI[g][j] = bi; accH[g][j] = bh; }
  }
  #pragma unroll
  for (int g = 0; g < 3; ++g){
    __syncthreads();
    for (int idx = t; idx < 4096; idx += 256){
      int row = idx >> 6, i = idx & 63;       // row = gate-output index
      wtI[i][row] = Wih[(size_t)(g*64+row)*64 + i];
      wtH[i][row] = Whh[(size_t)(g*64+row)*64 + i];
    }
    __syncthreads();
    for (int i = 0; i < 64; ++i){
      float wi = wtI[i][o], wh = wtH[i][o];
      #pragma unroll
      for (int j = 0; j < 4; ++j){
        int n = w*4 + j;
        accI[g][j] += ml[n][i]*wi;
        accH[g][j] += hl[n][i]*wh;
      }
    }
  }
  #pragma unroll
  for (int j = 0; j < 4; ++j){
    int n = w*4 + j;
    int v = blk*16 + n;
    if (v < NN){
      float r  = 1.f/(1.f+__expf(-(accI[0][j]+accH[0][j])));
      float z  = 1.f/(1.f+__expf(-(accI[1][j]+accH[1][j])));
      float nn_= tanhf(accI[2][j] + r*accH[2][j]);
      float hnew = (1.f - z)*nn_ + z*hl[n][o];
      hid[(size_t)v*DD + o] = hnew;
      hidb[(size_t)v*DD + o] = fsb(hnew);
      if (write_out) out[(size_t)v*DD + o] = hnew;
    }
  }
}

extern "C" void kernel_launch(void* const* d_in, const int* in_sizes, int n_in,
                              void* d_out, int out_size, void* d_ws, size_t ws_size,
                              hipStream_t stream){
  (void)out_size;
  float* out = (float*)d_out;

  // resolve input positions by size (== dict order on this instance)
  int p_nf=-1,p_ef=-1,p_src=-1,p_dst=-1,p_Wp=-1,p_bp=-1,p_W1=-1,p_b1=-1,
      p_W2=-1,p_b2=-1,p_cb=-1,p_gam=-1,p_bet=-1,p_Wih=-1,p_Whh=-1,p_bih=-1,p_bhh=-1;
  int c60000=0,c64=0,c12288=0,c192=0;
  for (int i = 0; i < n_in; ++i){
    switch (in_sizes[i]){
      case 1110000: p_nf = i; break;
      case 720000:  p_ef = i; break;
      case 60000:   if (c60000++ == 0) p_src = i; else p_dst = i; break;
      case 4736:    p_Wp = i; break;
      case 64:      { if (c64==0) p_bp=i; else if (c64==1) p_cb=i;
                      else if (c64==2) p_gam=i; else p_bet=i; c64++; } break;
      case 1536:    p_W1 = i; break;
      case 128:     p_b1 = i; break;
      case 524288:  p_W2 = i; break;
      case 4096:    p_b2 = i; break;
      case 12288:   if (c12288++ == 0) p_Wih = i; else p_Whh = i; break;
      case 192:     if (c192++ == 0) p_bih = i; else p_bhh = i; break;
      default: break;
    }
  }

  char* p = (char*)d_ws;
  auto alloc = [&](size_t bytes)->char*{
    char* r = p; p += (bytes + 255) & ~(size_t)255; return r;
  };
  int* flags = (int*)alloc(256);
  const int FPOS[15] = {p_nf,p_ef,p_Wp,p_bp,p_W1,p_b1,p_W2,p_b2,p_cb,p_gam,p_bet,
                        p_Wih,p_Whh,p_bih,p_bhh};
  CanonArgs ca;
  int maxn = 0;
  for (int j = 0; j < 15; ++j){
    int n = in_sizes[FPOS[j]];
    ca.in[j]  = d_in[FPOS[j]];
    ca.out[j] = (float*)alloc((size_t)n * 4);
    ca.n[j]   = n;
    if (n > maxn) maxn = n;
  }
  const float* nf  = ca.out[0];  const float* ef  = ca.out[1];
  const float* Wp  = ca.out[2];  const float* bp  = ca.out[3];
  const float* W1  = ca.out[4];  const float* b1  = ca.out[5];
  const float* W2  = ca.out[6];  const float* b2  = ca.out[7];
  const float* cb  = ca.out[8];  const float* gam = ca.out[9];
  const float* bet = ca.out[10]; const float* Wih = ca.out[11];
  const float* Whh = ca.out[12]; const float* bih = ca.out[13];
  const float* bhh = ca.out[14];
  int* srcc = (int*)alloc((size_t)NE*4);
  int* dstc = (int*)alloc((size_t)NE*4);

  float* tfp      = (float*)alloc((size_t)NE*EH*4);     // 30.7 MB
  ushort_t* w2rtx = (ushort_t*)alloc((size_t)NGX*DD*2); // 1.06 MB
  float* hid      = (float*)alloc((size_t)NN*DD*4);
  ushort_t* hidb  = (ushort_t*)alloc((size_t)NN*DD*2);
  float* msg      = (float*)alloc((size_t)NE*DD*4);     // 15.4 MB
  float* rst      = (float*)alloc((size_t)NN*DD*4);
  float* part     = (float*)alloc((size_t)NPART*128*4);
  float* stats    = (float*)alloc(128*4);
  int* degall     = (int*)alloc((size_t)4*NN*4);
  int* deg  = degall;        int* cursor  = degall + NN;
  int* deg2 = degall + 2*NN; int* cursor2 = degall + 3*NN;
  int* rowp   = (int*)alloc((size_t)(NN+1)*4);
  float* invd = (float*)alloc((size_t)NN*4);
  int* eidx   = (int*)alloc((size_t)NE*4);
  int* rowp2  = (int*)alloc((size_t)(NN+1)*4);
  float* invd2= (float*)alloc((size_t)NN*4);
  int* eidx2  = (int*)alloc((size_t)NE*4);

  // adaptive bf16 G-chunk (deterministic per ws_size); cap = full problem
  size_t used = (size_t)(p - (char*)d_ws);
  size_t rem = (ws_size > used) ? (ws_size - used) : 0;
  long long Cll = (long long)(rem / ((size_t)NGX*2));
  int C = (Cll > 15040) ? 15040 : (int)Cll;
  C &= ~63;
  if (C > 15040) C = 15040;
  if (C < 64)  C = 64;
  ushort_t* G = (ushort_t*)alloc((size_t)C*NGX*2);
  int nch = (NN + C - 1) / C;

  k_sniff<<<1, 256, 0, stream>>>((const ushort_t*)d_in[p_nf], (const int*)d_in[p_dst], flags);
  k_canon_all<<<dim3((maxn+255)/256, 15), 256, 0, stream>>>(ca, flags);
  k_canoni<<<(NE+255)/256, 256, 0, stream>>>(d_in[p_src], srcc, NE, flags);
  k_canoni<<<(NE+255)/256, 256, 0, stream>>>(d_in[p_dst], dstc, NE, flags);

  k_proj <<<NN/4,  256, 0, stream>>>(nf, Wp, bp, hid, hidb);
  k_emlp <<<NE/2,  256, 0, stream>>>(ef, W1, b1, tfp);
  k_w2rtx<<<(NGX*DD+255)/256, 256, 0, stream>>>(W2, b2, w2rtx);
  k_zero <<<(4*NN+255)/256, 256, 0, stream>>>(degall, 4*NN);
  k_deg  <<<(NE+255)/256, 256, 0, stream>>>(dstc, deg);
  k_deg  <<<(NE+255)/256, 256, 0, stream>>>(srcc, deg2);
  k_scan <<<1, 256, 0, stream>>>(deg, rowp, invd);
  k_scan <<<1, 256, 0, stream>>>(deg2, rowp2, invd2);
  k_scatter<<<(NE+255)/256, 256, 0, stream>>>(dstc, rowp, cursor, eidx);
  k_scatter<<<(NE+255)/256, 256, 0, stream>>>(srcc, rowp2, cursor2, eidx2);

  for (int s = 0; s < NSTEPS; ++s){
    for (int c = 0; c < nch; ++c){
      int chunk0 = c*C;
      int cact = (NN - chunk0 < C) ? (NN - chunk0) : C;
      k_ggemm<<<dim3(NGX/64, (cact+63)/64), 256, 0, stream>>>(hidb, w2rtx, G, chunk0, cact);
      k_edge <<<cact, 256, 0, stream>>>(tfp, G, rowp2, eidx2, msg, chunk0);
    }
    k_aggrbn<<<NPART, 256, 0, stream>>>(msg, rowp, eidx, invd, cb, rst, part);
    k_bnf   <<<1, 128, 0, stream>>>(part, stats);
    k_gru   <<<NPART, 256, 0, stream>>>(rst, stats, gam, bet, Wih, Whh, bih, bhh,
                                        hid, hidb, out, (s == NSTEPS-1) ? 1 : 0);
  }
}